// Round 6
// baseline (186.590 us; speedup 1.0000x reference)
//
#include <hip/hip_runtime.h>

typedef unsigned int u32;
typedef unsigned long long u64;

#define NB 32
#define NCLS 80
#define NANCHOR 8400
#define PRE 1000
#define MAXDET 100
#define NT 1024

// ---------------------------------------------------------------------------
// Kernel 1: decode all levels. Block = 64 quads (256 anchors).
// Phase 1: the 4 waves split the 80-class argmax into 20-class slices
// (wave w -> classes [20w,20w+20)), each lane owning one quad with float4
// loads; partials stored per-ANCHOR in LDS.
// Phase 2: one thread per anchor (all 256 threads): combine slices in
// ascending order (strict > keeps first-max), sigmoid, box decode, stores.
// ---------------------------------------------------------------------------
__global__ __launch_bounds__(256) void decode_kernel(
        const float* __restrict__ cls0, const float* __restrict__ box0,
        const float* __restrict__ cls1, const float* __restrict__ box1,
        const float* __restrict__ cls2, const float* __restrict__ box2,
        float* __restrict__ ws_scores, float4* __restrict__ ws_boxes,
        int* __restrict__ ws_cls) {
    const int NQ = NANCHOR / 4;                 // 2100 quads per image
    const int lane = threadIdx.x & 63;
    const int wv = threadIdx.x >> 6;            // class slice 0..3

    __shared__ float s_m[4][256];               // [slice][local anchor]
    __shared__ int   s_c[4][256];

    // ---- phase 1: per-quad slice argmax
    {
        const int q = blockIdx.x * 64 + lane;   // quad id (grid exact: 1050*64)
        int b = q / NQ;
        int r = (q - b * NQ) * 4;               // first anchor of the quad

        const float* cp;
        int HW, hw;
        if (r < 6400) {
            cp = cls0 + (size_t)b * NCLS * 6400; HW = 6400; hw = r;
        } else if (r < 8000) {
            cp = cls1 + (size_t)b * NCLS * 1600; HW = 1600; hw = r - 6400;
        } else {
            cp = cls2 + (size_t)b * NCLS * 400;  HW = 400;  hw = r - 8000;
        }

        const float* cps = cp + (size_t)(wv * 20) * HW + hw;
        float4 m = *(const float4*)cps;
        int c0 = wv * 20, c1 = c0, c2 = c0, c3 = c0;
#pragma unroll
        for (int c = 1; c < 20; ++c) {
            float4 v = *(const float4*)(cps + (size_t)c * HW);
            int cc = wv * 20 + c;
            if (v.x > m.x) { m.x = v.x; c0 = cc; }
            if (v.y > m.y) { m.y = v.y; c1 = cc; }
            if (v.z > m.z) { m.z = v.z; c2 = cc; }
            if (v.w > m.w) { m.w = v.w; c3 = cc; }
        }
        int a = lane * 4;                       // local anchor base
        s_m[wv][a + 0] = m.x; s_c[wv][a + 0] = c0;
        s_m[wv][a + 1] = m.y; s_c[wv][a + 1] = c1;
        s_m[wv][a + 2] = m.z; s_c[wv][a + 2] = c2;
        s_m[wv][a + 3] = m.w; s_c[wv][a + 3] = c3;
    }
    __syncthreads();

    // ---- phase 2: one anchor per thread (all 4 waves active)
    {
        const int t = threadIdx.x;              // local anchor 0..255
        const int ga = blockIdx.x * 256 + t;    // global anchor
        int b = ga / NANCHOR;
        int r = ga - b * NANCHOR;

        const float* bp;
        int HW, hw, rowlen, step;
        if (r < 6400) {
            bp = box0 + (size_t)b * 4 * 6400;
            HW = 6400; hw = r;        rowlen = 80; step = 8;
        } else if (r < 8000) {
            bp = box1 + (size_t)b * 4 * 1600;
            HW = 1600; hw = r - 6400; rowlen = 40; step = 16;
        } else {
            bp = box2 + (size_t)b * 4 * 400;
            HW = 400;  hw = r - 8000; rowlen = 20; step = 32;
        }

        // combine slices in ascending-class order: strict > keeps first max
        float mv = s_m[0][t]; int cv = s_c[0][t];
#pragma unroll
        for (int s = 1; s < 4; ++s) {
            float v = s_m[s][t];
            if (v > mv) { mv = v; cv = s_c[s][t]; }
        }

        float l  = bp[hw];
        float tt = bp[HW + hw];
        float rr = bp[2 * HW + hw];
        float bo = bp[3 * HW + hw];

        int h = hw / rowlen, w = hw - h * rowlen;
        float gy = (float)(h * step);
        float gx = (float)(w * step);

        ws_scores[ga] = 1.0f / (1.0f + expf(-mv));
        ws_boxes[ga] = make_float4(gx - l, gy - tt, gx + rr, gy + bo);
        ws_cls[ga] = cv;
    }
}

// ---------------------------------------------------------------------------
// helpers
// ---------------------------------------------------------------------------
__device__ __forceinline__ u64 shfl_xor_u64(u64 v, int m) {
    u32 lo = (u32)v, hi = (u32)(v >> 32);
    lo = (u32)__shfl_xor((int)lo, m, 64);
    hi = (u32)__shfl_xor((int)hi, m, 64);
    return ((u64)hi << 32) | (u64)lo;
}

__device__ __forceinline__ u64 readlane_u64(u64 v, int l) {
    u32 lo = (u32)v, hi = (u32)(v >> 32);
    lo = (u32)__builtin_amdgcn_readlane((int)lo, l);
    hi = (u32)__builtin_amdgcn_readlane((int)hi, l);
    return ((u64)hi << 32) | (u64)lo;
}

// inclusive suffix sum over sh[0..1023]; 3 barriers total.
__device__ __forceinline__ void suffix_scan_1024(int* sh, int* swsum, int* swadd) {
    const int tid = threadIdx.x, lane = tid & 63, wv = tid >> 6;
    int s = sh[tid];
#pragma unroll
    for (int off = 1; off < 64; off <<= 1) {
        int u = __shfl_down(s, off, 64);
        if (lane + off < 64) s += u;
    }
    if (lane == 0) swsum[wv] = s;          // wave total = suffix at lane 0
    __syncthreads();
    if (tid < 64) {
        int t = (lane < 16) ? swsum[lane] : 0;
#pragma unroll
        for (int off = 1; off < 16; off <<= 1) {
            int u = __shfl_down(t, off, 64);
            if (lane + off < 64) t += u;
        }
        int ab = __shfl_down(t, 1, 64);    // suffix of waves strictly above
        if (lane < 16) swadd[lane] = (lane == 15) ? 0 : ab;
    }
    __syncthreads();
    sh[tid] = s + swadd[wv];
    __syncthreads();
}

// ---------------------------------------------------------------------------
// Kernel 2: per-image radix-select + counting-rank ordering. Writes ONLY the
// sorted keys (box gather moved into iou_bits).
// cnt<=1024 (typical): all keys distinct (idx tiebreak; pads remapped to
// distinct tiny values) -> rank = #{keys > mine} is a permutation scatter.
// cnt>1024 (tie-storm): verified LDS bitonic fallback on 2048.
// ---------------------------------------------------------------------------
__global__ __launch_bounds__(NT) void select_sort_kernel(
        const float* __restrict__ ws_scores, u64* __restrict__ ws_keys) {
    const int b = blockIdx.x;
    const int tid = threadIdx.x;

    __shared__ int s_hist[1024];
    __shared__ u64 s_key[2048];
    __shared__ int s_wsum[16], s_wadd[16];
    __shared__ int s_C, s_base, s_cnt;
    __shared__ u32 s_thresh;

    const float* sc = ws_scores + (size_t)b * NANCHOR;

    s_hist[tid] = 0;
    s_key[tid] = 0ULL;
    s_key[tid + 1024] = 0ULL;
    if (tid == 0) s_cnt = 0;
    __syncthreads();

    // ---- pass 1: coarse histogram on bits [29:20]; cache bits in registers
    u32 sb[9];
#pragma unroll
    for (int k = 0; k < 9; ++k) {
        int a = tid + k * NT;
        if (a < NANCHOR) {
            u32 x = __float_as_uint(sc[a]);
            sb[k] = x;
            atomicAdd(&s_hist[x >> 20], 1);
        } else sb[k] = 0;
    }
    __syncthreads();
    suffix_scan_1024(s_hist, s_wsum, s_wadd);
    {
        int sfx = s_hist[tid];
        int nxt = (tid < 1023) ? s_hist[tid + 1] : 0;
        if (sfx >= PRE && (tid == 1023 || nxt < PRE)) { s_C = tid; s_base = nxt; }
    }
    __syncthreads();
    const int C = s_C, base = s_base;
    s_hist[tid] = 0;
    __syncthreads();

    // ---- pass 2: fine histogram on bits [19:10] within coarse bin C
#pragma unroll
    for (int k = 0; k < 9; ++k) {
        int a = tid + k * NT;
        if (a < NANCHOR && (int)(sb[k] >> 20) == C)
            atomicAdd(&s_hist[(sb[k] >> 10) & 1023], 1);
    }
    __syncthreads();
    suffix_scan_1024(s_hist, s_wsum, s_wadd);
    {
        int sfx = base + s_hist[tid];
        int nxt = base + ((tid < 1023) ? s_hist[tid + 1] : 0);
        if (sfx >= PRE && (tid == 1023 || nxt < PRE))
            s_thresh = ((u32)C << 20) | ((u32)tid << 10);
    }
    __syncthreads();
    const u32 thresh = s_thresh;

    // ---- compaction
#pragma unroll
    for (int k = 0; k < 9; ++k) {
        int a = tid + k * NT;
        if (a < NANCHOR && sb[k] >= thresh) {
            int pos = atomicAdd(&s_cnt, 1);
            if (pos < 2048)
                s_key[pos] = ((u64)sb[k] << 14) | (u64)(NANCHOR - 1 - a);
        }
    }
    __syncthreads();
    const int cnt = s_cnt;

    if (cnt > 1024) {
        // ---- fallback: LDS bitonic on 2048 (wave-sync for j<=32)
        bool prevBig = false;
        for (int k = 2; k <= 2048; k <<= 1) {
            for (int j = k >> 1; j > 0; j >>= 1) {
                const bool big = (j >= 64);
                if (big || prevBig) __syncthreads();
                else __builtin_amdgcn_wave_barrier();
                for (int i = tid; i < 2048; i += NT) {
                    int ixj = i ^ j;
                    if (ixj > i) {
                        u64 va = s_key[i], vb = s_key[ixj];
                        bool desc = ((i & k) == 0);
                        if (desc ? (va < vb) : (va > vb)) { s_key[i] = vb; s_key[ixj] = va; }
                    }
                }
                prevBig = big;
            }
        }
        __syncthreads();
    } else {
        // ---- counting-rank scatter (all keys distinct)
        // pads -> distinct tiny keys: real keys have score bits >= thresh >= 1
        // (thresh==0 implies cnt==8400 -> fallback), so (key >> 14) >= 1 and any
        // pad value (u64)tid <= 1023 < 2^14 sorts strictly below all real keys.
        if (tid >= cnt) s_key[tid] = (u64)tid;
        __syncthreads();
        const u64 my = s_key[tid];
        int rank = 0;
#pragma unroll 4
        for (int j = 0; j < 1024; j += 4) {
            u64 k0 = s_key[j + 0], k1 = s_key[j + 1];
            u64 k2 = s_key[j + 2], k3 = s_key[j + 3];
            rank += (int)(k0 > my) + (int)(k1 > my) + (int)(k2 > my) + (int)(k3 > my);
        }
        __syncthreads();
        s_key[rank] = my;      // permutation: no conflicts
        __syncthreads();
    }

    ws_keys[(b << 10) + tid] = s_key[tid];
}

// ---------------------------------------------------------------------------
// Kernel 3: suppression bitmap. Block = (image, 64-row tile); thread = (row, word).
// Each block gathers the sorted boxes itself (scattered reads, L2-resident,
// latency-hidden by 16 waves) and applies the class offset — identical fp
// expressions to the old select-side gather.
// bits[r][w] bit k = (IoU(r, w*64+k) > 0.5) && (w*64+k > r) && (w*64+k < 1000).
// ---------------------------------------------------------------------------
__global__ __launch_bounds__(1024) void iou_bits_kernel(
        const u64* __restrict__ ws_keys, const float4* __restrict__ ws_boxes,
        const int* __restrict__ ws_cls,
        u64* __restrict__ ws_bits, u64* __restrict__ ws_diag) {
    const int blk = blockIdx.x;
    const int b = blk >> 4, tile = blk & 15;
    const int tid = threadIdx.x;

    __shared__ float sx1[1024], sy1[1024], sx2[1024], sy2[1024], sar[1024];
    {
        u64 key = ws_keys[(b << 10) + tid];
        int idx = (NANCHOR - 1) - (int)(key & 16383ULL);
        float4 bx = ws_boxes[(size_t)b * NANCHOR + idx];
        int c = ws_cls[(size_t)b * NANCHOR + idx];
        float off = (float)c * 4096.0f;
        float x1 = bx.x + off, y1 = bx.y + off, x2 = bx.z + off, y2 = bx.w + off;
        sx1[tid] = x1; sy1[tid] = y1; sx2[tid] = x2; sy2[tid] = y2;
        sar[tid] = fmaxf(x2 - x1, 0.0f) * fmaxf(y2 - y1, 0.0f);
    }
    __syncthreads();

    const int rl = tid & 63, w = tid >> 6;
    const int r = (tile << 6) + rl;
    u64 bits = 0ULL;
    if (r < 1000 && w >= tile) {            // words below the diagonal are all-zero
        float xi1 = sx1[r], yi1 = sy1[r], xi2 = sx2[r], yi2 = sy2[r], ai = sar[r];
        const int jbase = w << 6;
#pragma unroll 8
        for (int kb = 0; kb < 64; ++kb) {
            int j = jbase + kb;             // broadcast LDS reads across the wave
            float lx = fmaxf(xi1, sx1[j]);
            float ly = fmaxf(yi1, sy1[j]);
            float rx = fminf(xi2, sx2[j]);
            float ry = fminf(yi2, sy2[j]);
            float wx = fmaxf(rx - lx, 0.0f);
            float wy = fmaxf(ry - ly, 0.0f);
            float inter = wx * wy;
            float iou = inter / (ai + sar[j] - inter + 1e-7f);
            bits |= (iou > 0.5f) ? (1ULL << kb) : 0ULL;
        }
        u64 mlow;                            // keep only j > r
        if (w == tile) {
            int bpos = r & 63;
            mlow = (bpos == 63) ? 0ULL : (~0ULL << (bpos + 1));
        } else mlow = ~0ULL;
        u64 mhigh = (jbase + 64 <= 1000) ? ~0ULL : ((1ULL << (1000 - jbase)) - 1ULL);
        bits &= mlow & mhigh;
    }
    ws_bits[((size_t)b << 14) + ((size_t)r << 4) + w] = bits;
    if (w == tile) ws_diag[(b << 10) + r] = bits;
}

// ---------------------------------------------------------------------------
// Kernel 4: per-image barrier-free greedy scan over the bitmap (wave 0 of a
// 128-thread block), then output.
// ---------------------------------------------------------------------------
__global__ __launch_bounds__(128) void nms_scan_kernel(
        const u64* __restrict__ ws_bits, const u64* __restrict__ ws_diag,
        const u64* __restrict__ ws_keys, const float4* __restrict__ ws_boxes,
        const int* __restrict__ ws_cls, float* __restrict__ out) {
    const int b = blockIdx.x;
    const int tid = threadIdx.x;

    __shared__ int s_keep[MAXDET];
    __shared__ int s_nk;

    if (tid < 64) {
        const int lane = tid;
        const u64* bits = ws_bits + ((size_t)b << 14);
        const u64* diag = ws_diag + ((size_t)b << 10);
        int nkept = 0;
        for (int wi = 0; wi < 16 && nkept < MAXDET; ++wi) {
            const int wbase = wi << 6;
            // state of this word from rows kept in earlier words
            u64 acc = 0ULL;
            if (lane < nkept)       acc  = bits[((size_t)s_keep[lane] << 4) + wi];
            if (lane + 64 < nkept)  acc |= bits[((size_t)s_keep[lane + 64] << 4) + wi];
#pragma unroll
            for (int off = 32; off > 0; off >>= 1) acc |= shfl_xor_u64(acc, off);
            u64 cur = acc;                          // uniform across the wave
            u64 rw = diag[wbase + lane];            // lane l holds word wi of row wbase+l
            const int nb = (wbase + 64 <= 1000) ? 64 : (1000 - wbase);
            for (int bit = 0; bit < nb; ++bit) {
                if (!((cur >> bit) & 1ULL)) {
                    if (lane == 0) s_keep[nkept] = wbase + bit;
                    nkept++;
                    if (nkept >= MAXDET) break;
                    cur |= readlane_u64(rw, bit);   // suppress within this word
                }
            }
        }
        if (lane == 0) s_nk = nkept;
    }
    __syncthreads();

    const int nk = s_nk;
    if (tid < MAXDET) {
        float* o = out + ((size_t)b * MAXDET + tid) * 5;
        float* oc = out + (size_t)NB * MAXDET * 5 + (size_t)b * MAXDET + tid;
        if (tid < nk) {
            int rank = s_keep[tid];
            u64 key = ws_keys[(b << 10) + rank];
            int idx = (NANCHOR - 1) - (int)(key & 16383ULL);
            float score = __uint_as_float((u32)(key >> 14));
            float4 bx = ws_boxes[(size_t)b * NANCHOR + idx];
            int c = ws_cls[(size_t)b * NANCHOR + idx];
            o[0] = bx.x; o[1] = bx.y; o[2] = bx.z; o[3] = bx.w; o[4] = score;
            *oc = (float)c;
        } else {
            o[0] = 0.0f; o[1] = 0.0f; o[2] = 0.0f; o[3] = 0.0f; o[4] = 0.0f;
            *oc = -1.0f;
        }
    }
}

extern "C" void kernel_launch(void* const* d_in, const int* in_sizes, int n_in,
                              void* d_out, int out_size, void* d_ws, size_t ws_size,
                              hipStream_t stream) {
    const float* cls0 = (const float*)d_in[0];
    const float* box0 = (const float*)d_in[1];
    const float* cls1 = (const float*)d_in[2];
    const float* box1 = (const float*)d_in[3];
    const float* cls2 = (const float*)d_in[4];
    const float* box2 = (const float*)d_in[5];

    float* ws = (float*)d_ws;
    float* ws_scores = ws;                                    // 268800 f32
    float4* ws_boxes = (float4*)(ws + NB * NANCHOR);          // 268800 float4
    int* ws_cls = (int*)(ws + (size_t)NB * NANCHOR * 5);      // 268800 int
    u64* ws_keys = (u64*)(ws + (size_t)NB * NANCHOR * 6);     // 32*1024 u64 (16B-aligned)
    u64* ws_bits = ws_keys + (size_t)NB * 1024;               // 32*1024*16 u64 = 4 MB
    u64* ws_diag = ws_bits + (size_t)NB * 1024 * 16;          // 32*1024 u64

    int nquads = NB * (NANCHOR / 4);            // 67200 = 1050 * 64 exactly
    decode_kernel<<<nquads / 64, 256, 0, stream>>>(
        cls0, box0, cls1, box1, cls2, box2, ws_scores, ws_boxes, ws_cls);

    select_sort_kernel<<<NB, NT, 0, stream>>>(ws_scores, ws_keys);

    iou_bits_kernel<<<NB * 16, 1024, 0, stream>>>(ws_keys, ws_boxes, ws_cls,
                                                  ws_bits, ws_diag);

    nms_scan_kernel<<<NB, 128, 0, stream>>>(ws_bits, ws_diag, ws_keys, ws_boxes, ws_cls,
                                            (float*)d_out);
}